// Round 2
// baseline (190.864 us; speedup 1.0000x reference)
//
#include <hip/hip_runtime.h>
#include <math.h>

// Problem constants (compile-time; graph structure is deterministic)
#define B_   128
#define N_   50
#define FIN  64
#define D_   64
#define BN   6400        // B*N
#define EPSF 1e-5f
// F(1,254) upper 0.05 critical value: pval > 0.05  <=>  fstat < FCRIT
#define FCRIT 3.8783305f

__device__ __forceinline__ float wsum(float v){
#pragma unroll
  for(int o=32;o>0;o>>=1) v += __shfl_xor(v,o);
  return v;
}
__device__ __forceinline__ float wmax(float v){
#pragma unroll
  for(int o=32;o>0;o>>=1) v = fmaxf(v,__shfl_xor(v,o));
  return v;
}
__device__ __forceinline__ float leaky(float x){ return x >= 0.f ? x : 0.2f*x; }

// K1: h = x @ W_lin (6400x64 @ 64x64); s_i, s_j per node.
__global__ __launch_bounds__(256) void k1_lin(
    const float* __restrict__ x, const float* __restrict__ W,
    const float* __restrict__ emb,
    const float* __restrict__ att_i, const float* __restrict__ att_j,
    const float* __restrict__ att_em_i, const float* __restrict__ att_em_j,
    float* __restrict__ h, float* __restrict__ s_i, float* __restrict__ s_j){
  __shared__ float wl[FIN*D_];
  __shared__ float xl[4*FIN];
  int tid = threadIdx.x;
  const float4* W4 = (const float4*)W;
  float4* wl4 = (float4*)wl;
  for(int i=tid;i<FIN*D_/4;i+=256) wl4[i] = W4[i];
  int r0 = blockIdx.x*4;
  xl[tid] = x[r0*FIN + tid];
  __syncthreads();
  int w = tid>>6, d = tid&63;
  int r = r0 + w;
  float acc = 0.f;
#pragma unroll
  for(int k=0;k<FIN;k++) acc += xl[w*FIN+k]*wl[k*D_+d];
  h[r*D_+d] = acc;
  int n = r % N_;
  float e = emb[n*D_+d];
  float vi = acc*att_i[d] + e*att_em_i[d];
  float vj = acc*att_j[d] + e*att_em_j[d];
  float si = wsum(vi);
  float sj = wsum(vj);
  if(d==0){ s_i[r]=si; s_j[r]=sj; }
}

// K2: per (b,p) full-softmax state; 50 submodel preds via one-term deletion.
// preds layout [sm][p][b]
__global__ __launch_bounds__(256) void k2_preds(
    const float* __restrict__ h, const float* __restrict__ s_i,
    const float* __restrict__ s_j, const float* __restrict__ emb,
    const float* __restrict__ gat_bias,
    const float* __restrict__ bn1_g, const float* __restrict__ bn1_b,
    const float* __restrict__ bn1_rm, const float* __restrict__ bn1_rv,
    const float* __restrict__ bn2_g, const float* __restrict__ bn2_b,
    const float* __restrict__ bn2_rm, const float* __restrict__ bn2_rv,
    const float* __restrict__ out_w, const float* __restrict__ out_b,
    float* __restrict__ preds){
  __shared__ float hl[N_*D_];
  int b = blockIdx.y, pg = blockIdx.x, tid = threadIdx.x;
  const float4* hsrc = (const float4*)(h + (size_t)b*N_*D_);
  float4* hl4 = (float4*)hl;
  for(int i=tid;i<N_*D_/4;i+=256) hl4[i] = hsrc[i];
  __syncthreads();
  int w = tid>>6, lane = tid&63;
  int p = pg*4 + w;
  if(p >= N_) return;                // only barrier already passed
  float sip = s_i[b*N_+p];
  float sjv = (lane<N_) ? s_j[b*N_+lane] : 0.f;
  float L = leaky(sip + sjv);
  float M = wmax(lane<N_ ? L : -3.0e38f);
  float e_ = (lane<N_) ? expf(L - M) : 0.f;
  float Dden = wsum(e_);
  float S = 0.f;
  for(int q=0;q<N_;q++){
    float eq = __shfl(e_, q);
    S += eq * hl[q*D_+lane];
  }
  int d = lane;
  float gb  = gat_bias[d];
  float rm1 = bn1_rm[d], i1g = bn1_g[d]/sqrtf(bn1_rv[d]+EPSF), b1v = bn1_b[d];
  float rm2 = bn2_rm[d], i2g = bn2_g[d]/sqrtf(bn2_rv[d]+EPSF), b2v = bn2_b[d];
  float embd = emb[p*D_+d];
  float ow = out_w[d];
  float ob = out_b[0];
  for(int sm=0;sm<N_;sm++){
    float num, den;
    if(sm==0){ num = S; den = Dden; }
    else {
      int s = sm-1;
      int qr = s + (s>=p);           // removed src for dst p in submodel sm
      float er = __shfl(e_, qr);
      num = S - er*hl[qr*D_+lane];
      den = Dden - er;
    }
    float o   = num/den + gb;
    float gcn = fmaxf((o - rm1)*i1g + b1v, 0.f);
    float x3  = gcn*embd;
    float xn  = fmaxf((x3 - rm2)*i2g + b2v, 0.f);
    float pr  = wsum(xn*ow) + ob;
    if(lane==0) preds[sm*BN + p*B_ + b] = pr;
  }
}

// K3: F-test per (s,p) over batch; keep[p*49+s] = !(fstat < FCRIT)
__global__ __launch_bounds__(64) void k3_ftest(
    const float* __restrict__ labels, const float* __restrict__ preds,
    int* __restrict__ keep){
  int blk = blockIdx.x;
  int s = blk / N_, p = blk % N_;
  int t = threadIdx.x;
  float l0 = labels[t*N_+p];
  float l1 = labels[(t+64)*N_+p];
  const float* P1 = preds + (size_t)(s+1)*BN + p*B_;
  const float* P0 = preds + (size_t)p*B_;
  float a0 = l0 - P1[t],    a1 = l1 - P1[t+64];
  float b0 = l0 - P0[t],    b1 = l1 - P0[t+64];
  float ma = wsum(a0+a1)*(1.f/B_);
  float mb = wsum(b0+b1)*(1.f/B_);
  float da0=a0-ma, da1=a1-ma, db0=b0-mb, db1=b1-mb;
  float ssw = wsum(da0*da0 + da1*da1 + db0*db0 + db1*db1);
  float g  = 0.5f*(ma+mb);
  float dA = ma-g, dB = mb-g;
  float ssb = (float)B_ * (dA*dA + dB*dB);
  float f = ssb / (ssw / 254.0f);
  int kv = (f < FCRIT) ? 0 : 1;      // NaN -> keep (matches reference)
  if(t==0) keep[p*(N_-1)+s] = kv;
}

// K4a: final-model masked softmax attention -> out_raw[b*N+p][d]
__global__ __launch_bounds__(256) void k4a_out(
    const float* __restrict__ h, const float* __restrict__ s_i,
    const float* __restrict__ s_j, const int* __restrict__ keep,
    const float* __restrict__ gat_bias, float* __restrict__ out_raw){
  __shared__ float hl[N_*D_];
  int b = blockIdx.y, pg = blockIdx.x, tid = threadIdx.x;
  const float4* hsrc = (const float4*)(h + (size_t)b*N_*D_);
  float4* hl4 = (float4*)hl;
  for(int i=tid;i<N_*D_/4;i+=256) hl4[i] = hsrc[i];
  __syncthreads();
  int w = tid>>6, lane = tid&63;
  int p = pg*4 + w;
  if(p >= N_) return;
  float sip = s_i[b*N_+p];
  float sjv = (lane<N_) ? s_j[b*N_+lane] : 0.f;
  float L = leaky(sip + sjv);
  bool allowed = false;
  if(lane < N_){
    if(lane == p) allowed = true;    // self-loop always on
    else {
      int idx = (lane < p) ? lane : lane-1;
      allowed = keep[p*(N_-1)+idx] != 0;
    }
  }
  float Lv = allowed ? L : -1.0e9f;  // NEG, matches reference masking
  float M = wmax(lane<N_ ? Lv : -3.0e38f);
  float e_ = allowed ? expf(L - M) : 0.f;
  float den = wsum(e_);
  float alpha = e_/den;
  float o = 0.f;
  for(int q=0;q<N_;q++){
    float aq = __shfl(alpha, q);
    o += aq * hl[q*D_+lane];
  }
  o += gat_bias[lane];
  out_raw[(size_t)(b*N_+p)*D_+lane] = o;
}

// K4b: per-channel train-mode BN stats (two-pass mean/var, then x3 stats)
__global__ __launch_bounds__(256) void k4b_stats(
    const float* __restrict__ out_raw, const float* __restrict__ emb,
    const float* __restrict__ bn1_g, const float* __restrict__ bn1_b,
    float* __restrict__ stats){
  __shared__ float red[4];
  int d = blockIdx.x, tid = threadIdx.x, w = tid>>6, lane = tid&63;
  float s = 0.f;
  for(int r=tid;r<BN;r+=256) s += out_raw[(size_t)r*D_+d];
  s = wsum(s); if(lane==0) red[w]=s; __syncthreads();
  float mu1 = (red[0]+red[1]+red[2]+red[3])*(1.f/BN); __syncthreads();
  float s2 = 0.f;
  for(int r=tid;r<BN;r+=256){ float v=out_raw[(size_t)r*D_+d]-mu1; s2+=v*v; }
  s2 = wsum(s2); if(lane==0) red[w]=s2; __syncthreads();
  float var1 = (red[0]+red[1]+red[2]+red[3])*(1.f/BN); __syncthreads();
  float i1g = bn1_g[d]/sqrtf(var1+EPSF), b1v = bn1_b[d];
  float s3 = 0.f;
  for(int r=tid;r<BN;r+=256){
    float v = out_raw[(size_t)r*D_+d];
    float gcn = fmaxf((v-mu1)*i1g+b1v, 0.f);
    s3 += gcn*emb[(r%N_)*D_+d];
  }
  s3 = wsum(s3); if(lane==0) red[w]=s3; __syncthreads();
  float mu2 = (red[0]+red[1]+red[2]+red[3])*(1.f/BN); __syncthreads();
  float s4 = 0.f;
  for(int r=tid;r<BN;r+=256){
    float v = out_raw[(size_t)r*D_+d];
    float gcn = fmaxf((v-mu1)*i1g+b1v, 0.f);
    float u = gcn*emb[(r%N_)*D_+d] - mu2;
    s4 += u*u;
  }
  s4 = wsum(s4); if(lane==0) red[w]=s4; __syncthreads();
  float var2 = (red[0]+red[1]+red[2]+red[3])*(1.f/BN);
  if(tid==0){ stats[d]=mu1; stats[64+d]=var1; stats[128+d]=mu2; stats[192+d]=var2; }
}

// K4c: final head -> d_out[b*N+p]
__global__ __launch_bounds__(256) void k4c_final(
    const float* __restrict__ out_raw, const float* __restrict__ emb,
    const float* __restrict__ bn1_g, const float* __restrict__ bn1_b,
    const float* __restrict__ bn2_g, const float* __restrict__ bn2_b,
    const float* __restrict__ out_w, const float* __restrict__ out_b,
    const float* __restrict__ stats, float* __restrict__ outp){
  int tid = threadIdx.x, w = tid>>6, lane = tid&63;
  int r = blockIdx.x*4 + w;
  int d = lane;
  float mu1 = stats[d], var1 = stats[64+d], mu2 = stats[128+d], var2 = stats[192+d];
  float i1g = bn1_g[d]/sqrtf(var1+EPSF), b1v = bn1_b[d];
  float i2g = bn2_g[d]/sqrtf(var2+EPSF), b2v = bn2_b[d];
  float v = out_raw[(size_t)r*D_+d];
  float gcn = fmaxf((v-mu1)*i1g+b1v, 0.f);
  float x3  = gcn*emb[(r%N_)*D_+d];
  float xn  = fmaxf((x3-mu2)*i2g+b2v, 0.f);
  float pr  = wsum(xn*out_w[d]) + out_b[0];
  if(lane==0) outp[r] = pr;
}

extern "C" void kernel_launch(void* const* d_in, const int* in_sizes, int n_in,
                              void* d_out, int out_size, void* d_ws, size_t ws_size,
                              hipStream_t stream){
  (void)in_sizes; (void)n_in; (void)out_size; (void)ws_size;
  const float* data     = (const float*)d_in[0];
  const float* labels   = (const float*)d_in[1];
  // d_in[2..6]: edge_index / src_b / dst_b / submodel_masks / removed_edge_id
  // -> deterministic, reconstructed at compile time; not read.
  const float* emb      = (const float*)d_in[7];
  const float* W_lin    = (const float*)d_in[8];
  const float* att_i    = (const float*)d_in[9];
  const float* att_j    = (const float*)d_in[10];
  const float* att_em_i = (const float*)d_in[11];
  const float* att_em_j = (const float*)d_in[12];
  const float* gat_bias = (const float*)d_in[13];
  const float* bn1_g    = (const float*)d_in[14];
  const float* bn1_b    = (const float*)d_in[15];
  const float* bn1_rm   = (const float*)d_in[16];
  const float* bn1_rv   = (const float*)d_in[17];
  const float* bn2_g    = (const float*)d_in[18];
  const float* bn2_b    = (const float*)d_in[19];
  const float* bn2_rm   = (const float*)d_in[20];
  const float* bn2_rv   = (const float*)d_in[21];
  const float* out_w    = (const float*)d_in[22];
  const float* out_b    = (const float*)d_in[23];

  float* ws      = (float*)d_ws;
  float* h       = ws;                 // 409600
  float* s_i     = ws + 409600;        // 6400
  float* s_j     = ws + 416000;        // 6400
  float* preds   = ws + 422400;        // 320000 (dead after k3)
  float* out_raw = ws + 422400;        // 409600 (overlaps preds; k4a runs after k3)
  int*   keep    = (int*)(ws + 832000);// 2450
  float* stats   = ws + 834560;        // 256
  float* outp    = (float*)d_out;

  hipLaunchKernelGGL(k1_lin, dim3(BN/4), dim3(256), 0, stream,
                     data, W_lin, emb, att_i, att_j, att_em_i, att_em_j, h, s_i, s_j);
  hipLaunchKernelGGL(k2_preds, dim3(13, B_), dim3(256), 0, stream,
                     h, s_i, s_j, emb, gat_bias,
                     bn1_g, bn1_b, bn1_rm, bn1_rv,
                     bn2_g, bn2_b, bn2_rm, bn2_rv,
                     out_w, out_b, preds);
  hipLaunchKernelGGL(k3_ftest, dim3((N_-1)*N_), dim3(64), 0, stream,
                     labels, preds, keep);
  hipLaunchKernelGGL(k4a_out, dim3(13, B_), dim3(256), 0, stream,
                     h, s_i, s_j, keep, gat_bias, out_raw);
  hipLaunchKernelGGL(k4b_stats, dim3(D_), dim3(256), 0, stream,
                     out_raw, emb, bn1_g, bn1_b, stats);
  hipLaunchKernelGGL(k4c_final, dim3(BN/4), dim3(256), 0, stream,
                     out_raw, emb, bn1_g, bn1_b, bn2_g, bn2_b, out_w, out_b, stats, outp);
}

// Round 4
// 157.147 us; speedup vs baseline: 1.2146x; 1.2146x over previous
//
#include <hip/hip_runtime.h>
#include <math.h>

#define B_   128
#define N_   50
#define FIN  64
#define D_   64
#define BN   6400        // B*N
#define EPSF 1e-5f
// F(1,254) upper 0.05 critical value: pval > 0.05  <=>  fstat < FCRIT
#define FCRIT 3.8783305f

__device__ __forceinline__ float wsum(float v){
#pragma unroll
  for(int o=32;o>0;o>>=1) v += __shfl_xor(v,o);
  return v;
}
__device__ __forceinline__ float wmax(float v){
#pragma unroll
  for(int o=32;o>0;o>>=1) v = fmaxf(v,__shfl_xor(v,o));
  return v;
}
__device__ __forceinline__ float leaky(float x){ return x >= 0.f ? x : 0.2f*x; }

// K0: fold BN/head constants; zero the atomic stats accumulators.
// hc4[d] = (A = i1g, C1 = i1g*gb + b1 - rm1*i1g, C2 = b2 - rm2*i2g, ow)
__global__ __launch_bounds__(256) void k0_prep(
    const float* __restrict__ bn1_g, const float* __restrict__ bn1_b,
    const float* __restrict__ bn1_rm, const float* __restrict__ bn1_rv,
    const float* __restrict__ bn2_g, const float* __restrict__ bn2_b,
    const float* __restrict__ bn2_rm, const float* __restrict__ bn2_rv,
    const float* __restrict__ gat_bias, const float* __restrict__ out_w,
    float4* __restrict__ hc4, float* __restrict__ hci2g,
    float* __restrict__ stats_raw){
  int t = threadIdx.x;
  stats_raw[t] = 0.f;                 // 256 accumulators
  if(t < 64){
    float i1g = bn1_g[t]/sqrtf(bn1_rv[t]+EPSF);
    float i2g = bn2_g[t]/sqrtf(bn2_rv[t]+EPSF);
    float C1 = i1g*gat_bias[t] + bn1_b[t] - bn1_rm[t]*i1g;
    float C2 = bn2_b[t] - bn2_rm[t]*i2g;
    hc4[t] = make_float4(i1g, C1, C2, out_w[t]);
    hci2g[t] = i2g;
  }
}

// K1: h = x @ W_lin; s_i, s_j per node. 8 rows/block.
__global__ __launch_bounds__(256) void k1_lin(
    const float* __restrict__ x, const float* __restrict__ W,
    const float* __restrict__ emb,
    const float* __restrict__ att_i, const float* __restrict__ att_j,
    const float* __restrict__ att_em_i, const float* __restrict__ att_em_j,
    float* __restrict__ h, float* __restrict__ s_i, float* __restrict__ s_j){
  __shared__ float wl[FIN*D_];
  __shared__ float xl[8*FIN];
  int tid = threadIdx.x;
  const float4* W4 = (const float4*)W;
  float4* wl4 = (float4*)wl;
  for(int i=tid;i<FIN*D_/4;i+=256) wl4[i] = W4[i];
  int r0 = blockIdx.x*8;
  { const float4* x4 = (const float4*)(x + (size_t)r0*FIN);
    float4* xl4 = (float4*)xl;
    for(int i=tid;i<8*FIN/4;i+=256) xl4[i] = x4[i]; }
  __syncthreads();
  int w = tid>>6, d = tid&63;
  float acc0 = 0.f, acc1 = 0.f;
#pragma unroll
  for(int k=0;k<FIN;k++){
    float wv = wl[k*D_+d];
    acc0 = fmaf(xl[(w*2+0)*FIN+k], wv, acc0);
    acc1 = fmaf(xl[(w*2+1)*FIN+k], wv, acc1);
  }
  float ai = att_i[d], aj = att_j[d], aei = att_em_i[d], aej = att_em_j[d];
#pragma unroll
  for(int j=0;j<2;j++){
    int r = r0 + w*2 + j;
    float acc = j ? acc1 : acc0;
    h[(size_t)r*D_+d] = acc;
    int n = r % N_;
    float e = emb[n*D_+d];
    float si = wsum(acc*ai + e*aei);
    float sj = wsum(acc*aj + e*aej);
    if(d==0){ s_i[r]=si; s_j[r]=sj; }
  }
}

// K2: per (b,p): softmax state once, 50 submodels via one-term deletion.
// Shuffle-free phase layout; preds[p][b][64-padded sm].
__global__ __launch_bounds__(256) void k2_preds(
    const float* __restrict__ h, const float* __restrict__ s_i,
    const float* __restrict__ s_j, const float* __restrict__ emb,
    const float* __restrict__ out_b,
    const float4* __restrict__ hc4, const float* __restrict__ hci2g,
    float* __restrict__ preds){
  __shared__ float hT[64*53];
  __shared__ float el[4*64];
  __shared__ float2 wc[4*64];
  int b = blockIdx.y, tid = threadIdx.x;
  const float* hb = h + (size_t)b*N_*D_;
  for(int i=tid;i<N_*D_;i+=256) hT[(i&63)*53 + (i>>6)] = hb[i];
  __syncthreads();
  int w = tid>>6, lane = tid&63;
  int p = blockIdx.x*4 + w;
  if(p >= N_) return;
  // Phase A (lane = q): softmax state
  float sip = s_i[b*N_+p];
  float L = -3.0e38f;
  if(lane < N_) L = leaky(sip + s_j[b*N_+lane]);
  float M = wmax(L);
  float e = (lane < N_) ? expf(L - M) : 0.f;
  float Dden = wsum(e);
  el[w*64+lane] = e;
  // Phase B (lane = d): S_d = sum_q e_q hT[d][q]; Em_d = emb_pd * i2g_d
  float S = 0.f;
  const float* hTd = &hT[lane*53];
  const float* elw = &el[w*64];
#pragma unroll 10
  for(int q=0;q<N_;q++) S = fmaf(elw[q], hTd[q], S);
  float Em = emb[p*D_+lane]*hci2g[lane];
  wc[w*64+lane] = make_float2(S, Em);
  // Phase C (lane = sm): serial 64-d head, zero shuffles
  float er = 0.f; int r = 0;
  if(lane >= 1 && lane < N_){
    int s = lane-1; r = s + (s>=p ? 1 : 0); er = el[w*64+r];
  }
  float den  = Dden - er;
  float beta = 1.f/den;
  float alpha = er*beta;
  float acc = out_b[0];
  const float2* wcw = &wc[w*64];
#pragma unroll 8
  for(int d=0;d<64;d++){
    float4 hc = hc4[d];              // uniform -> scalar load
    float2 se = wcw[d];              // LDS broadcast
    float hrd = hT[d*53 + r];        // lane-varying, <=2-way bank
    float o  = fmaf(-alpha, hrd, se.x*beta);
    float g  = fmaxf(fmaf(hc.x, o, hc.y), 0.f);
    float xn = fmaxf(fmaf(g, se.y, hc.z), 0.f);
    acc = fmaf(xn, hc.w, acc);
  }
  if(lane < N_) preds[((size_t)p*B_ + b)*64 + lane] = acc;
}

// K3: F-test per (s,p); keep[p*49+s] = (f >= FCRIT) (NaN -> keep)
__global__ __launch_bounds__(64) void k3_ftest(
    const float* __restrict__ labels, const float* __restrict__ preds,
    int* __restrict__ keep){
  int blk = blockIdx.x;
  int s = blk / N_, p = blk % N_;
  int t = threadIdx.x;
  float l0 = labels[t*N_+p];
  float l1 = labels[(t+64)*N_+p];
  float a0 = l0 - preds[((size_t)p*B_ + t   )*64 + (s+1)];
  float a1 = l1 - preds[((size_t)p*B_ + t+64)*64 + (s+1)];
  float b0 = l0 - preds[((size_t)p*B_ + t   )*64];
  float b1 = l1 - preds[((size_t)p*B_ + t+64)*64];
  float ma = wsum(a0+a1)*(1.f/B_);
  float mb = wsum(b0+b1)*(1.f/B_);
  float da0=a0-ma, da1=a1-ma, db0=b0-mb, db1=b1-mb;
  float ssw = wsum(da0*da0 + da1*da1 + db0*db0 + db1*db1);
  float g  = 0.5f*(ma+mb);
  float dA = ma-g, dB = mb-g;
  float ssb = (float)B_ * (dA*dA + dB*dB);
  float f = ssb / (ssw / 254.0f);
  int kv = (f < FCRIT) ? 0 : 1;
  if(t==0) keep[p*(N_-1)+s] = kv;
}

// K4a: final-model masked attention -> out_raw[b*N+p][d], shuffle-free
__global__ __launch_bounds__(256) void k4a_out(
    const float* __restrict__ h, const float* __restrict__ s_i,
    const float* __restrict__ s_j, const int* __restrict__ keep,
    const float* __restrict__ gat_bias, float* __restrict__ out_raw){
  __shared__ float hT[64*53];
  __shared__ float al[4*64];
  int b = blockIdx.y, tid = threadIdx.x;
  const float* hb = h + (size_t)b*N_*D_;
  for(int i=tid;i<N_*D_;i+=256) hT[(i&63)*53 + (i>>6)] = hb[i];
  __syncthreads();
  int w = tid>>6, lane = tid&63;
  int p = blockIdx.x*4 + w;
  if(p >= N_) return;
  float sip = s_i[b*N_+p];
  float L = -3.0e38f; bool allowed = false;
  if(lane < N_){
    float Lr = leaky(sip + s_j[b*N_+lane]);
    if(lane == p) allowed = true;
    else { int idx = (lane < p) ? lane : lane-1; allowed = keep[p*(N_-1)+idx] != 0; }
    L = allowed ? Lr : -1.0e9f;
  }
  float M = wmax(L);
  float e = allowed ? expf(L - M) : 0.f;
  float D = wsum(e);
  al[w*64+lane] = e;
  float invD = 1.f/D;
  float o = 0.f;
  const float* hTd = &hT[lane*53];
  const float* alw = &al[w*64];
#pragma unroll 10
  for(int q=0;q<N_;q++) o = fmaf(alw[q], hTd[q], o);
  out_raw[((size_t)b*N_+p)*D_ + lane] = o*invD + gat_bias[lane];
}

// K4b1: Σo, Σo² per channel (coalesced rows, atomics into stats_raw[0..127])
__global__ __launch_bounds__(256) void k4b1_stats(
    const float* __restrict__ out_raw, float* __restrict__ stats_raw){
  __shared__ float2 red[4][64];
  int tid = threadIdx.x, w = tid>>6, lane = tid&63;
  int r0 = blockIdx.x*64;
  float s1=0.f, s2=0.f;
  for(int i=w;i<64;i+=4){
    float o = out_raw[(size_t)(r0+i)*D_ + lane];
    s1 += o; s2 = fmaf(o,o,s2);
  }
  red[w][lane] = make_float2(s1,s2);
  __syncthreads();
  if(w==0){
    float2 a=red[0][lane], b=red[1][lane], c=red[2][lane], d=red[3][lane];
    atomicAdd(&stats_raw[lane],      a.x+b.x+c.x+d.x);
    atomicAdd(&stats_raw[64+lane],   a.y+b.y+c.y+d.y);
  }
}

// K4b2: Σx3, Σx3² per channel (x3 = relu(bn1-train(o))*emb), into [128..255]
__global__ __launch_bounds__(256) void k4b2_stats(
    const float* __restrict__ out_raw, const float* __restrict__ emb,
    const float* __restrict__ bn1_g, const float* __restrict__ bn1_b,
    float* __restrict__ stats_raw){
  __shared__ float2 red[4][64];
  int tid = threadIdx.x, w = tid>>6, lane = tid&63;
  int r0 = blockIdx.x*64;
  float mu1  = stats_raw[lane]     * (1.f/BN);
  float var1 = stats_raw[64+lane]  * (1.f/BN) - mu1*mu1;
  float A = bn1_g[lane]/sqrtf(var1+EPSF);
  float C = bn1_b[lane] - mu1*A;
  float s1=0.f, s2=0.f;
  for(int i=w;i<64;i+=4){
    int r = r0+i;
    float o = out_raw[(size_t)r*D_ + lane];
    float g = fmaxf(fmaf(A,o,C), 0.f);
    float x3 = g*emb[(r%N_)*D_ + lane];
    s1 += x3; s2 = fmaf(x3,x3,s2);
  }
  red[w][lane] = make_float2(s1,s2);
  __syncthreads();
  if(w==0){
    float2 a=red[0][lane], b=red[1][lane], c=red[2][lane], d=red[3][lane];
    atomicAdd(&stats_raw[128+lane],  a.x+b.x+c.x+d.x);
    atomicAdd(&stats_raw[192+lane],  a.y+b.y+c.y+d.y);
  }
}

// K4c: final head -> d_out[b*N+p]; 16 rows/block
__global__ __launch_bounds__(256) void k4c_final(
    const float* __restrict__ out_raw, const float* __restrict__ emb,
    const float* __restrict__ bn1_g, const float* __restrict__ bn1_b,
    const float* __restrict__ bn2_g, const float* __restrict__ bn2_b,
    const float* __restrict__ out_w, const float* __restrict__ out_b,
    const float* __restrict__ stats_raw, float* __restrict__ outp){
  int tid = threadIdx.x, w = tid>>6, lane = tid&63;
  float mu1  = stats_raw[lane]     * (1.f/BN);
  float var1 = stats_raw[64+lane]  * (1.f/BN) - mu1*mu1;
  float mu2  = stats_raw[128+lane] * (1.f/BN);
  float var2 = stats_raw[192+lane] * (1.f/BN) - mu2*mu2;
  float A1 = bn1_g[lane]/sqrtf(var1+EPSF);
  float C1 = bn1_b[lane] - mu1*A1;
  float A2 = bn2_g[lane]/sqrtf(var2+EPSF);
  float C2 = bn2_b[lane] - mu2*A2;
  float ow = out_w[lane], ob = out_b[0];
#pragma unroll
  for(int j=0;j<4;j++){
    int r = blockIdx.x*16 + w*4 + j;
    float o = out_raw[(size_t)r*D_ + lane];
    float g = fmaxf(fmaf(A1,o,C1), 0.f);
    float x3 = g*emb[(r%N_)*D_ + lane];
    float xn = fmaxf(fmaf(A2,x3,C2), 0.f);
    float pr = wsum(xn*ow);
    if(lane==0) outp[r] = pr + ob;
  }
}

extern "C" void kernel_launch(void* const* d_in, const int* in_sizes, int n_in,
                              void* d_out, int out_size, void* d_ws, size_t ws_size,
                              hipStream_t stream){
  (void)in_sizes; (void)n_in; (void)out_size; (void)ws_size;
  const float* data     = (const float*)d_in[0];
  const float* labels   = (const float*)d_in[1];
  // d_in[2..6]: graph indices / masks — deterministic, not read.
  const float* emb      = (const float*)d_in[7];
  const float* W_lin    = (const float*)d_in[8];
  const float* att_i    = (const float*)d_in[9];
  const float* att_j    = (const float*)d_in[10];
  const float* att_em_i = (const float*)d_in[11];
  const float* att_em_j = (const float*)d_in[12];
  const float* gat_bias = (const float*)d_in[13];
  const float* bn1_g    = (const float*)d_in[14];
  const float* bn1_b    = (const float*)d_in[15];
  const float* bn1_rm   = (const float*)d_in[16];
  const float* bn1_rv   = (const float*)d_in[17];
  const float* bn2_g    = (const float*)d_in[18];
  const float* bn2_b    = (const float*)d_in[19];
  const float* bn2_rm   = (const float*)d_in[20];
  const float* bn2_rv   = (const float*)d_in[21];
  const float* out_w    = (const float*)d_in[22];
  const float* out_b    = (const float*)d_in[23];

  float* ws      = (float*)d_ws;
  float* h       = ws;                     // 409600
  float* s_i     = ws + 409600;            // 6400
  float* s_j     = ws + 416000;            // 6400
  float* preds   = ws + 422400;            // 409600 ([p][b][64]; dead after k3)
  float* out_raw = ws + 422400;            // overlays preds (k4a after k3)
  int*   keep    = (int*)(ws + 832000);    // 2450
  float* stats   = ws + 834560;            // 256 (atomic accumulators)
  float4* hc4    = (float4*)(ws + 834816); // 64 float4
  float* hci2g   = ws + 835072;            // 64
  float* outp    = (float*)d_out;

  hipLaunchKernelGGL(k0_prep, dim3(1), dim3(256), 0, stream,
                     bn1_g, bn1_b, bn1_rm, bn1_rv, bn2_g, bn2_b, bn2_rm, bn2_rv,
                     gat_bias, out_w, hc4, hci2g, stats);
  hipLaunchKernelGGL(k1_lin, dim3(BN/8), dim3(256), 0, stream,
                     data, W_lin, emb, att_i, att_j, att_em_i, att_em_j, h, s_i, s_j);
  hipLaunchKernelGGL(k2_preds, dim3(13, B_), dim3(256), 0, stream,
                     h, s_i, s_j, emb, out_b, hc4, hci2g, preds);
  hipLaunchKernelGGL(k3_ftest, dim3((N_-1)*N_), dim3(64), 0, stream,
                     labels, preds, keep);
  hipLaunchKernelGGL(k4a_out, dim3(13, B_), dim3(256), 0, stream,
                     h, s_i, s_j, keep, gat_bias, out_raw);
  hipLaunchKernelGGL(k4b1_stats, dim3(BN/64), dim3(256), 0, stream,
                     out_raw, stats);
  hipLaunchKernelGGL(k4b2_stats, dim3(BN/64), dim3(256), 0, stream,
                     out_raw, emb, bn1_g, bn1_b, stats);
  hipLaunchKernelGGL(k4c_final, dim3(BN/16), dim3(256), 0, stream,
                     out_raw, emb, bn1_g, bn1_b, bn2_g, bn2_b, out_w, out_b, stats, outp);
}

// Round 5
// 142.926 us; speedup vs baseline: 1.3354x; 1.0995x over previous
//
#include <hip/hip_runtime.h>
#include <math.h>

#define B_   128
#define N_   50
#define FIN  64
#define D_   64
#define BN   6400        // B*N
#define EPSF 1e-5f
// F(1,254) upper 0.05 critical value: pval > 0.05  <=>  fstat < FCRIT
#define FCRIT 3.8783305f

__device__ __forceinline__ float wsum(float v){
#pragma unroll
  for(int o=32;o>0;o>>=1) v += __shfl_xor(v,o);
  return v;
}
__device__ __forceinline__ float wmax(float v){
#pragma unroll
  for(int o=32;o>0;o>>=1) v = fmaxf(v,__shfl_xor(v,o));
  return v;
}
__device__ __forceinline__ float leaky(float x){ return x >= 0.f ? x : 0.2f*x; }

// K1: h = x @ W_lin; s_i, s_j per node. 8 rows/block.
// Block 0 additionally: fold eval-BN/head constants, zero acc + stats slots.
__global__ __launch_bounds__(256) void k1_lin(
    const float* __restrict__ x, const float* __restrict__ W,
    const float* __restrict__ emb,
    const float* __restrict__ att_i, const float* __restrict__ att_j,
    const float* __restrict__ att_em_i, const float* __restrict__ att_em_j,
    const float* __restrict__ bn1_g, const float* __restrict__ bn1_b,
    const float* __restrict__ bn1_rm, const float* __restrict__ bn1_rv,
    const float* __restrict__ bn2_g, const float* __restrict__ bn2_b,
    const float* __restrict__ bn2_rm, const float* __restrict__ bn2_rv,
    const float* __restrict__ gat_bias, const float* __restrict__ out_w,
    float* __restrict__ h, float* __restrict__ s_i, float* __restrict__ s_j,
    float2* __restrict__ acc, float* __restrict__ statz /*2048*/,
    float4* __restrict__ hc4, float* __restrict__ hci2g){
  __shared__ float wl[FIN*D_];
  __shared__ float xl[8*FIN];
  int tid = threadIdx.x;
  const float4* W4 = (const float4*)W;
  float4* wl4 = (float4*)wl;
  for(int i=tid;i<FIN*D_/4;i+=256) wl4[i] = W4[i];
  int r0 = blockIdx.x*8;
  { const float4* x4 = (const float4*)(x + (size_t)r0*FIN);
    float4* xl4 = (float4*)xl;
    for(int i=tid;i<8*FIN/4;i+=256) xl4[i] = x4[i]; }
  __syncthreads();
  int w = tid>>6, d = tid&63;
  float acc0 = 0.f, acc1 = 0.f;
#pragma unroll
  for(int k=0;k<FIN;k++){
    float wv = wl[k*D_+d];
    acc0 = fmaf(xl[(w*2+0)*FIN+k], wv, acc0);
    acc1 = fmaf(xl[(w*2+1)*FIN+k], wv, acc1);
  }
  float ai = att_i[d], aj = att_j[d], aei = att_em_i[d], aej = att_em_j[d];
#pragma unroll
  for(int j=0;j<2;j++){
    int r = r0 + w*2 + j;
    float a_ = j ? acc1 : acc0;
    h[(size_t)r*D_+d] = a_;
    int n = r % N_;
    float e = emb[n*D_+d];
    float si = wsum(a_*ai + e*aei);
    float sj = wsum(a_*aj + e*aej);
    if(d==0){ s_i[r]=si; s_j[r]=sj; }
  }
  if(blockIdx.x==0){
    for(int i=tid;i<N_*N_;i+=256) acc[i] = make_float2(0.f,0.f);
    for(int i=tid;i<2048;i+=256)  statz[i] = 0.f;
    if(tid < 64){
      float i1g = bn1_g[tid]/sqrtf(bn1_rv[tid]+EPSF);
      float i2g = bn2_g[tid]/sqrtf(bn2_rv[tid]+EPSF);
      float C1 = i1g*gat_bias[tid] + bn1_b[tid] - bn1_rm[tid]*i1g;
      float C2 = bn2_b[tid] - bn2_rm[tid]*i2g;
      hc4[tid] = make_float4(i1g, C1, C2, out_w[tid]);
      hci2g[tid] = i2g;
    }
  }
}

// K2: per (b,p): softmax state once; 50 submodel preds by one-term deletion;
// residual moments accumulated atomically into acc[p*50+sm] = (Σr, Σr²).
__global__ __launch_bounds__(512) void k2_preds(
    const float* __restrict__ h, const float* __restrict__ s_i,
    const float* __restrict__ s_j, const float* __restrict__ labels,
    const float* __restrict__ emb, const float* __restrict__ out_b,
    const float4* __restrict__ hc4, const float* __restrict__ hci2g,
    float2* __restrict__ acc){
  __shared__ float hT[64*53];
  __shared__ float el[8*64];
  __shared__ float2 wc[8*64];
  int b = blockIdx.y, tid = threadIdx.x;
  const float* hb = h + (size_t)b*N_*D_;
  for(int i=tid;i<N_*D_;i+=512) hT[(i&63)*53 + (i>>6)] = hb[i];
  __syncthreads();
  int w = tid>>6, lane = tid&63;
  int p = blockIdx.x*8 + w;
  if(p >= N_) return;
  // Phase A (lane = q): softmax state
  float sip = s_i[b*N_+p];
  float L = -3.0e38f;
  if(lane < N_) L = leaky(sip + s_j[b*N_+lane]);
  float M = wmax(L);
  float e = (lane < N_) ? expf(L - M) : 0.f;
  float Dden = wsum(e);
  el[w*64+lane] = e;
  // Phase B (lane = d): S_d; Em_d = emb_pd * i2g_d
  float S = 0.f;
  const float* hTd = &hT[lane*53];
  const float* elw = &el[w*64];
#pragma unroll 10
  for(int q=0;q<N_;q++) S = fmaf(elw[q], hTd[q], S);
  wc[w*64+lane] = make_float2(S, emb[p*D_+lane]*hci2g[lane]);
  // Phase C (lane = sm): serial 64-d head, zero shuffles
  float er = 0.f; int r = 0;
  if(lane >= 1 && lane < N_){
    int s = lane-1; r = s + (s>=p ? 1 : 0); er = el[w*64+r];
  }
  float beta = 1.f/(Dden - er);
  float alpha = er*beta;
  float acc_ = out_b[0];
  const float2* wcw = &wc[w*64];
#pragma unroll 8
  for(int d=0;d<64;d++){
    float4 hc = hc4[d];              // uniform -> scalar load
    float2 se = wcw[d];              // LDS broadcast
    float hrd = hT[d*53 + r];        // lane-varying, <=2-way bank
    float o  = fmaf(-alpha, hrd, se.x*beta);
    float g  = fmaxf(fmaf(hc.x, o, hc.y), 0.f);
    float xn = fmaxf(fmaf(g, se.y, hc.z), 0.f);
    acc_ = fmaf(xn, hc.w, acc_);
  }
  if(lane < N_){
    float resid = labels[b*N_+p] - acc_;
    atomicAdd(&acc[p*N_+lane].x, resid);
    atomicAdd(&acc[p*N_+lane].y, resid*resid);
  }
}

// K4a: inline F-test -> keep bits (per-wave LDS), masked attention -> out_raw,
// epilogue: per-block (Σo, Σo²) into stats1[slot][128] (8-slot spread atomics).
__global__ __launch_bounds__(512) void k4a_out(
    const float* __restrict__ h, const float* __restrict__ s_i,
    const float* __restrict__ s_j, const float2* __restrict__ acc,
    const float* __restrict__ gat_bias,
    float* __restrict__ out_raw, float* __restrict__ stats1){
  __shared__ float hT[64*53];
  __shared__ float al[8*64];
  __shared__ int   keepL[8*64];
  __shared__ float2 red[8][64];
  int b = blockIdx.y, tid = threadIdx.x;
  const float* hb = h + (size_t)b*N_*D_;
  for(int i=tid;i<N_*D_;i+=512) hT[(i&63)*53 + (i>>6)] = hb[i];
  __syncthreads();
  int w = tid>>6, lane = tid&63;
  int p = blockIdx.x*8 + w;
  bool act = (p < N_);
  float o = 0.f;
  if(act){
    // F-test for (s=lane, p): ssw via moments, ssb = 64*(ma-mb)^2
    int kb = 1;
    if(lane < N_-1){
      float2 A2 = acc[p*N_ + lane + 1];
      float2 B2 = acc[p*N_];
      float ma = A2.x*(1.f/B_), mb = B2.x*(1.f/B_);
      float ssw = (A2.y - (float)B_*ma*ma) + (B2.y - (float)B_*mb*mb);
      float dmb = ma - mb;
      float f = (64.f*dmb*dmb) / (ssw*(1.f/254.f));
      kb = (f < FCRIT) ? 0 : 1;      // NaN -> keep (matches reference)
    }
    keepL[w*64+lane] = kb;           // same-wave write/read: no barrier
    float sip = s_i[b*N_+p];
    float L = -3.0e38f; bool allowed = false;
    if(lane < N_){
      float Lr = leaky(sip + s_j[b*N_+lane]);
      if(lane == p) allowed = true;  // self-loop always on
      else { int idx = (lane < p) ? lane : lane-1; allowed = keepL[w*64+idx] != 0; }
      L = allowed ? Lr : -1.0e9f;
    }
    float M = wmax(L);
    float e = allowed ? expf(L - M) : 0.f;
    float Dn = wsum(e);
    al[w*64+lane] = e;
    float invD = 1.f/Dn;
    float s = 0.f;
    const float* hTd = &hT[lane*53];
    const float* alw = &al[w*64];
#pragma unroll 10
    for(int q=0;q<N_;q++) s = fmaf(alw[q], hTd[q], s);
    o = s*invD + gat_bias[lane];
    out_raw[((size_t)b*N_+p)*D_ + lane] = o;
  }
  red[w][lane] = act ? make_float2(o, o*o) : make_float2(0.f, 0.f);
  __syncthreads();
  if(w==0){
    float s1=0.f, s2=0.f;
#pragma unroll
    for(int k=0;k<8;k++){ float2 v = red[k][lane]; s1+=v.x; s2+=v.y; }
    int slot = b & 7;
    atomicAdd(&stats1[slot*128 + lane],      s1);
    atomicAdd(&stats1[slot*128 + 64 + lane], s2);
  }
}

// K4b: x3-stats pass (needs global mu1/var1 from stats1) -> stats2 slots
__global__ __launch_bounds__(256) void k4b_stats(
    const float* __restrict__ out_raw, const float* __restrict__ emb,
    const float* __restrict__ bn1_g, const float* __restrict__ bn1_b,
    const float* __restrict__ stats1, float* __restrict__ stats2){
  __shared__ float2 red[4][64];
  int tid = threadIdx.x, w = tid>>6, lane = tid&63;
  float t1=0.f, t2=0.f;
#pragma unroll
  for(int k=0;k<8;k++){ t1 += stats1[k*128+lane]; t2 += stats1[k*128+64+lane]; }
  float mu1  = t1*(1.f/BN);
  float var1 = t2*(1.f/BN) - mu1*mu1;
  float A = bn1_g[lane]/sqrtf(var1+EPSF);
  float C = bn1_b[lane] - mu1*A;
  int r0 = blockIdx.x*64;
  float s1=0.f, s2=0.f;
  for(int i=w;i<64;i+=4){
    int r = r0+i;
    float o = out_raw[(size_t)r*D_ + lane];
    float g = fmaxf(fmaf(A,o,C), 0.f);
    float x3 = g*emb[(r%N_)*D_ + lane];
    s1 += x3; s2 = fmaf(x3,x3,s2);
  }
  red[w][lane] = make_float2(s1,s2);
  __syncthreads();
  if(w==0){
    float2 a=red[0][lane], b=red[1][lane], c=red[2][lane], d=red[3][lane];
    int slot = blockIdx.x & 7;
    atomicAdd(&stats2[slot*128 + lane],      a.x+b.x+c.x+d.x);
    atomicAdd(&stats2[slot*128 + 64 + lane], a.y+b.y+c.y+d.y);
  }
}

// K4c: final head -> d_out[b*N+p]; 16 rows/block
__global__ __launch_bounds__(256) void k4c_final(
    const float* __restrict__ out_raw, const float* __restrict__ emb,
    const float* __restrict__ bn1_g, const float* __restrict__ bn1_b,
    const float* __restrict__ bn2_g, const float* __restrict__ bn2_b,
    const float* __restrict__ out_w, const float* __restrict__ out_b,
    const float* __restrict__ stats1, const float* __restrict__ stats2,
    float* __restrict__ outp){
  int tid = threadIdx.x, w = tid>>6, lane = tid&63;
  float t1=0.f, t2=0.f, t3=0.f, t4=0.f;
#pragma unroll
  for(int k=0;k<8;k++){
    t1 += stats1[k*128+lane]; t2 += stats1[k*128+64+lane];
    t3 += stats2[k*128+lane]; t4 += stats2[k*128+64+lane];
  }
  float mu1  = t1*(1.f/BN), var1 = t2*(1.f/BN) - mu1*mu1;
  float mu2  = t3*(1.f/BN), var2 = t4*(1.f/BN) - mu2*mu2;
  float A1 = bn1_g[lane]/sqrtf(var1+EPSF);
  float C1 = bn1_b[lane] - mu1*A1;
  float A2 = bn2_g[lane]/sqrtf(var2+EPSF);
  float C2 = bn2_b[lane] - mu2*A2;
  float ow = out_w[lane], ob = out_b[0];
#pragma unroll
  for(int j=0;j<4;j++){
    int r = blockIdx.x*16 + w*4 + j;
    float o = out_raw[(size_t)r*D_ + lane];
    float g = fmaxf(fmaf(A1,o,C1), 0.f);
    float x3 = g*emb[(r%N_)*D_ + lane];
    float xn = fmaxf(fmaf(A2,x3,C2), 0.f);
    float pr = wsum(xn*ow);
    if(lane==0) outp[r] = pr + ob;
  }
}

extern "C" void kernel_launch(void* const* d_in, const int* in_sizes, int n_in,
                              void* d_out, int out_size, void* d_ws, size_t ws_size,
                              hipStream_t stream){
  (void)in_sizes; (void)n_in; (void)out_size; (void)ws_size;
  const float* data     = (const float*)d_in[0];
  const float* labels   = (const float*)d_in[1];
  // d_in[2..6]: graph indices / masks — deterministic, not read.
  const float* emb      = (const float*)d_in[7];
  const float* W_lin    = (const float*)d_in[8];
  const float* att_i    = (const float*)d_in[9];
  const float* att_j    = (const float*)d_in[10];
  const float* att_em_i = (const float*)d_in[11];
  const float* att_em_j = (const float*)d_in[12];
  const float* gat_bias = (const float*)d_in[13];
  const float* bn1_g    = (const float*)d_in[14];
  const float* bn1_b    = (const float*)d_in[15];
  const float* bn1_rm   = (const float*)d_in[16];
  const float* bn1_rv   = (const float*)d_in[17];
  const float* bn2_g    = (const float*)d_in[18];
  const float* bn2_b    = (const float*)d_in[19];
  const float* bn2_rm   = (const float*)d_in[20];
  const float* bn2_rv   = (const float*)d_in[21];
  const float* out_w    = (const float*)d_in[22];
  const float* out_b    = (const float*)d_in[23];

  float*  ws      = (float*)d_ws;
  float*  h       = ws;                      // 409600
  float*  s_i     = ws + 409600;             // 6400
  float*  s_j     = ws + 416000;             // 6400
  float*  out_raw = ws + 422400;             // 409600 -> 832000
  float2* acc     = (float2*)(ws + 832000);  // 2500 float2 -> 837000
  float*  stats1  = ws + 837000;             // 1024 -> 838024
  float*  stats2  = ws + 838024;             // 1024 -> 839048
  float4* hc4     = (float4*)(ws + 839048);  // 64 float4 (16B-aligned) -> 839304
  float*  hci2g   = ws + 839304;             // 64
  float*  outp    = (float*)d_out;

  hipLaunchKernelGGL(k1_lin, dim3(BN/8), dim3(256), 0, stream,
                     data, W_lin, emb, att_i, att_j, att_em_i, att_em_j,
                     bn1_g, bn1_b, bn1_rm, bn1_rv, bn2_g, bn2_b, bn2_rm, bn2_rv,
                     gat_bias, out_w, h, s_i, s_j, acc, stats1, hc4, hci2g);
  hipLaunchKernelGGL(k2_preds, dim3(7, B_), dim3(512), 0, stream,
                     h, s_i, s_j, labels, emb, out_b, hc4, hci2g, acc);
  hipLaunchKernelGGL(k4a_out, dim3(7, B_), dim3(512), 0, stream,
                     h, s_i, s_j, acc, gat_bias, out_raw, stats1);
  hipLaunchKernelGGL(k4b_stats, dim3(BN/64), dim3(256), 0, stream,
                     out_raw, emb, bn1_g, bn1_b, stats1, stats2);
  hipLaunchKernelGGL(k4c_final, dim3(BN/16), dim3(256), 0, stream,
                     out_raw, emb, bn1_g, bn1_b, bn2_g, bn2_b, out_w, out_b,
                     stats1, stats2, outp);
}